// Round 20
// baseline (217.506 us; speedup 1.0000x reference)
//
#include <hip/hip_runtime.h>
#include <hip/hip_bf16.h>

#define N_NODES 50000
#define N_EDGES 800000
#define N_GRAPHS 64
#define HID 64
#define SCAN_NB 196  // ceil(50000/256)
#define FILL_RANGES 8
#define RANGE_SIZE ((N_NODES + FILL_RANGES - 1) / FILL_RANGES)  // 6250
#define MM1_BLOCKS ((N_NODES + 63) / 64)                        // 782
#define FILL_BLOCKS (FILL_RANGES * ((N_EDGES + 255) / 256))     // 25000

static inline size_t align256(size_t x) { return (x + 255) & ~(size_t)255; }

typedef __attribute__((ext_vector_type(8))) short short8v;
typedef __attribute__((ext_vector_type(4))) float f32x4;

// bf16 helpers (bit-level, RNE) -- storage compression + MFMA input prep.
__device__ __forceinline__ unsigned short f2bf(float f) {
    unsigned int u = __float_as_uint(f);
    unsigned int r = (u + 0x7fffu + ((u >> 16) & 1u)) >> 16;
    return (unsigned short)r;
}
__device__ __forceinline__ float bf2f(unsigned short h) {
    return __uint_as_float(((unsigned int)h) << 16);
}

// zero two disjoint int ranges in one launch (cnt | gsum+gmax)
__global__ void zero2(int* __restrict__ a, int na, int* __restrict__ b, int nb) {
    int i = blockIdx.x * blockDim.x + threadIdx.x;
    if (i < na) a[i] = 0;
    else if (i < na + nb) b[i - na] = 0;
}

// count incoming edges per destination node (nontemporal: ei is streamed,
// never reused by this kernel -- keep cnt lines L2-resident)
__global__ void deg_kernel(const int* __restrict__ ei, int* __restrict__ cnt) {
    int e = blockIdx.x * blockDim.x + threadIdx.x;
    if (e < N_EDGES) atomicAdd(&cnt[__builtin_nontemporal_load(&ei[N_EDGES + e])], 1);
}

// phase A: per-block (256-wide) inclusive scan of cnt; block totals to bsum
// (round-17 lesson: decoupled-lookback single-kernel scan serializes through
// a device-atomic chain, +14us; the 3 tiny grid-parallel launches win)
__global__ __launch_bounds__(256) void scan_a(const int* __restrict__ cnt,
                                              int* __restrict__ incl,
                                              int* __restrict__ bsum) {
    __shared__ int sd[256];
    int t = threadIdx.x;
    int i = blockIdx.x * 256 + t;
    int v = (i < N_NODES) ? cnt[i] : 0;
    sd[t] = v;
    __syncthreads();
    for (int off = 1; off < 256; off <<= 1) {
        int u = (t >= off) ? sd[t - off] : 0;
        __syncthreads();
        sd[t] += u;
        __syncthreads();
    }
    if (i < N_NODES) incl[i] = sd[t];
    if (t == 255) bsum[blockIdx.x] = sd[255];
}

// phase B (+gstart fused): threads 0..255 scan the block sums; threads
// 256..320 binary-search gstart (batch sorted). All threads hit every barrier.
__global__ __launch_bounds__(384) void scan_b_gstart(const int* __restrict__ bsum,
                                                     int* __restrict__ boff,
                                                     const int* __restrict__ batch,
                                                     int* __restrict__ gstart) {
    __shared__ int sd[256];
    int t = threadIdx.x;
    int v = 0;
    if (t < 256) {
        v = (t < SCAN_NB) ? bsum[t] : 0;
        sd[t] = v;
    }
    __syncthreads();
    for (int off = 1; off < 256; off <<= 1) {
        int u = (t < 256 && t >= off) ? sd[t - off] : 0;
        __syncthreads();
        if (t < 256) sd[t] += u;
        __syncthreads();
    }
    if (t < SCAN_NB) boff[t] = sd[t] - v;  // exclusive
    if (t >= 256 && t - 256 <= N_GRAPHS) {
        int g = t - 256;
        int lo = 0, hi = N_NODES;
        while (lo < hi) {
            int mid = (lo + hi) >> 1;
            if (batch[mid] < g) lo = mid + 1; else hi = mid;
        }
        gstart[g] = lo;
    }
}

// phase C: writeback row_ptr / fill_ptr / dinv
__global__ void scan_c(const int* __restrict__ cnt, const int* __restrict__ incl,
                       const int* __restrict__ boff, int* __restrict__ row_ptr,
                       int* __restrict__ fill_ptr, float* __restrict__ dinv) {
    int i = blockIdx.x * blockDim.x + threadIdx.x;
    if (i < N_NODES) {
        int c = cnt[i];
        int run = boff[i >> 8] + incl[i];  // inclusive prefix over all nodes
        row_ptr[i + 1] = run;
        fill_ptr[i] = run - c;             // bucket start
        dinv[i] = rsqrtf((float)c + 1.0f);
        if (i == 0) row_ptr[0] = 0;
    }
}

// DUAL-ROLE kernel: blocks [0, MM1_BLOCKS) run the layer-1 MFMA matmul;
// blocks [MM1_BLOCKS, ...) run the XCD-partitioned CSR scatter (round-8:
// one csr region written from one XCD; class (bid-MM1_BLOCKS)&7 is a fixed
// bid%8 residue). csr_src is uint16. Round-19: ei/x reads are NONTEMPORAL --
// streaming reads were evicting partially-filled csr lines from the XCD's
// 4MB L2, causing ~27MB of repeated writebacks (WRITE_SIZE 35MB vs ~8MB
// ideal). Non-allocate reads keep csr lines resident until complete.
// MM part: hw2 = bf16(dinv * (x @ W1)), 3-term hi/lo bf16 split; W fragments
// pre-swizzled in LDS; D layout (m89): row=(l>>4)*4+j, col=l&15.
__global__ __launch_bounds__(256) void fill_mm1_kernel(const int* __restrict__ ei,
                                                       int* __restrict__ fill_ptr,
                                                       unsigned short* __restrict__ csr_src,
                                                       const float* __restrict__ h,
                                                       const float* __restrict__ W,
                                                       const float* __restrict__ dinv,
                                                       unsigned short* __restrict__ hw2) {
    constexpr int K = 128;
    constexpr int NSTEP = K / 32;
    __shared__ unsigned short sWH[NSTEP * 4 * 64 * 8];
    __shared__ unsigned short sWL[NSTEP * 4 * 64 * 8];
    int tid = threadIdx.x;

    if (blockIdx.x >= MM1_BLOCKS) {
        // ---- fill role ----
        int fb = blockIdx.x - MM1_BLOCKS;
        int r = fb & (FILL_RANGES - 1);
        int e = (fb >> 3) * 256 + tid;
        if (e >= N_EDGES) return;
        int dst = __builtin_nontemporal_load(&ei[N_EDGES + e]);
        int lo = r * RANGE_SIZE;
        if (dst >= lo && dst < lo + RANGE_SIZE) {
            int src = __builtin_nontemporal_load(&ei[e]);
            int pos = atomicAdd(&fill_ptr[dst], 1);
            csr_src[pos] = (unsigned short)src;
        }
        return;
    }

    // ---- mm role ----
    int r0 = blockIdx.x * 64;
#pragma unroll 1
    for (int ent = tid; ent < NSTEP * 4 * 64; ent += 256) {
        int lane_e = ent & 63;
        int c = (ent >> 6) & 3;
        int step = ent >> 8;
        int kb = step * 32 + (lane_e >> 4) * 8;
        int n = c * 16 + (lane_e & 15);
#pragma unroll
        for (int j = 0; j < 8; ++j) {
            float f = W[(kb + j) * 64 + n];
            unsigned short hi = f2bf(f);
            sWH[ent * 8 + j] = hi;
            sWL[ent * 8 + j] = f2bf(f - bf2f(hi));
        }
    }
    __syncthreads();

    int lane = tid & 63;
    int wid = tid >> 6;
    int arow = min(r0 + wid * 16 + (lane & 15), N_NODES - 1);  // clamp; write guarded
    const float* ap = h + (size_t)arow * K;
    int klane = (lane >> 4) * 8;

    f32x4 acc[4];
#pragma unroll
    for (int c = 0; c < 4; ++c) acc[c] = (f32x4){0.f, 0.f, 0.f, 0.f};

#pragma unroll 1
    for (int step = 0; step < NSTEP; ++step) {
        int kb = step * 32 + klane;
        float4 f0, f1;
        f0.x = __builtin_nontemporal_load(&ap[kb + 0]);
        f0.y = __builtin_nontemporal_load(&ap[kb + 1]);
        f0.z = __builtin_nontemporal_load(&ap[kb + 2]);
        f0.w = __builtin_nontemporal_load(&ap[kb + 3]);
        f1.x = __builtin_nontemporal_load(&ap[kb + 4]);
        f1.y = __builtin_nontemporal_load(&ap[kb + 5]);
        f1.z = __builtin_nontemporal_load(&ap[kb + 6]);
        f1.w = __builtin_nontemporal_load(&ap[kb + 7]);
        float fv[8] = {f0.x, f0.y, f0.z, f0.w, f1.x, f1.y, f1.z, f1.w};
        short8v ahi, alo;
#pragma unroll
        for (int j = 0; j < 8; ++j) {
            unsigned short hi = f2bf(fv[j]);
            ahi[j] = (short)hi;
            alo[j] = (short)f2bf(fv[j] - bf2f(hi));
        }
#pragma unroll
        for (int c = 0; c < 4; ++c) {
            short8v bh = *(const short8v*)&sWH[((step * 4 + c) * 64 + lane) * 8];
            short8v bl = *(const short8v*)&sWL[((step * 4 + c) * 64 + lane) * 8];
            acc[c] = __builtin_amdgcn_mfma_f32_16x16x32_bf16(ahi, bh, acc[c], 0, 0, 0);
            acc[c] = __builtin_amdgcn_mfma_f32_16x16x32_bf16(alo, bh, acc[c], 0, 0, 0);
            acc[c] = __builtin_amdgcn_mfma_f32_16x16x32_bf16(ahi, bl, acc[c], 0, 0, 0);
        }
    }

    int rb = r0 + wid * 16 + (lane >> 4) * 4;
#pragma unroll
    for (int j = 0; j < 4; ++j) {
        int row = rb + j;
        if (row < N_NODES) {
            float dv = dinv[row];
#pragma unroll
            for (int c = 0; c < 4; ++c) {
                hw2[(size_t)row * 64 + c * 16 + (lane & 15)] = f2bf(dv * acc[c][j]);
            }
        }
    }
}

// FUSED agg + next-layer MFMA matmul. 1024 threads = 16 waves = 16 nodes
// (50000 = 3125*16 exact, no tail -> barrier-safe). Gather 8-wide
// MLP-unrolled (round-14/16); wave-uniform shfl (round-5). Waves deposit
// normalized h rows into a 16x68-padded LDS tile, barrier, waves 0-3 each
// compute one 16-col tile of h @ Wn via the same 3-term hi/lo MFMA as the
// standalone mm64 (bit-identical arithmetic).
__global__ __launch_bounds__(1024) void aggmm_kernel(const unsigned short* __restrict__ hw_in,
                                                     const int* __restrict__ row_ptr,
                                                     const unsigned short* __restrict__ csr_src,
                                                     const float* __restrict__ dinv,
                                                     const float* __restrict__ b,
                                                     const float* __restrict__ Wn,
                                                     unsigned short* __restrict__ hw_out) {
    __shared__ unsigned short sWH[2 * 4 * 64 * 8];  // 8 KB
    __shared__ unsigned short sWL[2 * 4 * 64 * 8];  // 8 KB
    __shared__ float hlds[16 * 68];                 // padded stride 68
    int tid = threadIdx.x;

    if (tid < 512) {
        int ent = tid;
        int lane_e = ent & 63;
        int c = (ent >> 6) & 3;
        int step = ent >> 8;
        int kb = step * 32 + (lane_e >> 4) * 8;
        int n = c * 16 + (lane_e & 15);
#pragma unroll
        for (int j = 0; j < 8; ++j) {
            float f = Wn[(kb + j) * 64 + n];
            unsigned short hi = f2bf(f);
            sWH[ent * 8 + j] = hi;
            sWL[ent * 8 + j] = f2bf(f - bf2f(hi));
        }
    }

    int wid = tid >> 6;
    int node = blockIdx.x * 16 + wid;
    int lane = tid & 63;
    int grp = lane >> 3;
    int gl  = lane & 7;
    int s = row_ptr[node], e = row_ptr[node + 1];

    float acc[8] = {0.f, 0.f, 0.f, 0.f, 0.f, 0.f, 0.f, 0.f};
    for (int base = s; base < e; base += 64) {
        int nE = min(64, e - base);
        int msrc = (lane < nE) ? (int)csr_src[base + lane] : 0;
#pragma unroll
        for (int rr = 0; rr < 8; ++rr) {
            int i = rr * 8;
            if (i >= nE) break;
            int myi = i + grp;
            int src = __shfl(msrc, myi, 64);
            bool ok = myi < nE;
            int srcx = ok ? src : node;
            short8v v = *(const short8v*)&hw_in[(size_t)srcx * 64 + gl * 8];
            if (ok) {
#pragma unroll
                for (int j = 0; j < 8; ++j) acc[j] += bf2f((unsigned short)v[j]);
            }
        }
    }
#pragma unroll
    for (int off = 8; off <= 32; off <<= 1) {
#pragma unroll
        for (int j = 0; j < 8; ++j) acc[j] += __shfl_xor(acc[j], off, 64);
    }
    short8v sv = *(const short8v*)&hw_in[(size_t)node * 64 + gl * 8];
#pragma unroll
    for (int j = 0; j < 8; ++j) acc[j] += bf2f((unsigned short)sv[j]);

    float di = dinv[node];
    float4 b0 = *(const float4*)&b[gl * 8];
    float4 b1 = *(const float4*)&b[gl * 8 + 4];
    float val[8];
    val[0] = di * acc[0] + b0.x;
    val[1] = di * acc[1] + b0.y;
    val[2] = di * acc[2] + b0.z;
    val[3] = di * acc[3] + b0.w;
    val[4] = di * acc[4] + b1.x;
    val[5] = di * acc[5] + b1.y;
    val[6] = di * acc[6] + b1.z;
    val[7] = di * acc[7] + b1.w;

    float sq = 0.f;
#pragma unroll
    for (int j = 0; j < 8; ++j) sq += val[j] * val[j];
#pragma unroll
    for (int off = 1; off <= 4; off <<= 1) sq += __shfl_xor(sq, off, 64);
    float inv = 1.0f / fmaxf(sqrtf(sq), 1e-12f);

    if (grp == 0) {
        float4 r0, r1;
        r0.x = fmaxf(val[0] * inv, 0.f);
        r0.y = fmaxf(val[1] * inv, 0.f);
        r0.z = fmaxf(val[2] * inv, 0.f);
        r0.w = fmaxf(val[3] * inv, 0.f);
        r1.x = fmaxf(val[4] * inv, 0.f);
        r1.y = fmaxf(val[5] * inv, 0.f);
        r1.z = fmaxf(val[6] * inv, 0.f);
        r1.w = fmaxf(val[7] * inv, 0.f);
        *(float4*)&hlds[wid * 68 + gl * 8] = r0;
        *(float4*)&hlds[wid * 68 + gl * 8 + 4] = r1;
    }
    __syncthreads();

    if (wid < 4) {
        int klane = (lane >> 4) * 8;
        f32x4 macc = (f32x4){0.f, 0.f, 0.f, 0.f};
#pragma unroll
        for (int step = 0; step < 2; ++step) {
            const float* hr = &hlds[(lane & 15) * 68 + step * 32 + klane];
            short8v ahi, alo;
#pragma unroll
            for (int j = 0; j < 8; ++j) {
                float f = hr[j];
                unsigned short hi = f2bf(f);
                ahi[j] = (short)hi;
                alo[j] = (short)f2bf(f - bf2f(hi));
            }
            short8v bh = *(const short8v*)&sWH[((step * 4 + wid) * 64 + lane) * 8];
            short8v bl = *(const short8v*)&sWL[((step * 4 + wid) * 64 + lane) * 8];
            macc = __builtin_amdgcn_mfma_f32_16x16x32_bf16(ahi, bh, macc, 0, 0, 0);
            macc = __builtin_amdgcn_mfma_f32_16x16x32_bf16(alo, bh, macc, 0, 0, 0);
            macc = __builtin_amdgcn_mfma_f32_16x16x32_bf16(ahi, bl, macc, 0, 0, 0);
        }
        int rb = blockIdx.x * 16 + (lane >> 4) * 4;
#pragma unroll
        for (int j = 0; j < 4; ++j) {
            int row = rb + j;
            hw_out[(size_t)row * 64 + wid * 16 + (lane & 15)] = f2bf(dinv[row] * macc[j]);
        }
    }
}

// Final agg (layer 3) + fused pooling: 256 threads, 4 nodes/block (grid
// exact N_NODES/4). Block's 4 rows -> LDS, 64 threads run-combine per dim
// (batch sorted), ~1 atomicAdd+atomicMax per dim/block.
__global__ __launch_bounds__(256) void agg_pool_kernel(const unsigned short* __restrict__ hw2,
                                                       const int* __restrict__ row_ptr,
                                                       const unsigned short* __restrict__ csr_src,
                                                       const float* __restrict__ dinv,
                                                       const float* __restrict__ b,
                                                       const int* __restrict__ batch,
                                                       float* __restrict__ gsum,
                                                       float* __restrict__ gmax) {
    __shared__ float sh[4][64];
    int tid = threadIdx.x;
    int node = blockIdx.x * 4 + (tid >> 6);
    int lane = tid & 63;
    int grp = lane >> 3;
    int gl  = lane & 7;
    int s = row_ptr[node], e = row_ptr[node + 1];

    float acc[8] = {0.f, 0.f, 0.f, 0.f, 0.f, 0.f, 0.f, 0.f};
    for (int base = s; base < e; base += 64) {
        int nE = min(64, e - base);
        int msrc = (lane < nE) ? (int)csr_src[base + lane] : 0;
#pragma unroll
        for (int rr = 0; rr < 8; ++rr) {
            int i = rr * 8;
            if (i >= nE) break;
            int myi = i + grp;
            int src = __shfl(msrc, myi, 64);
            bool ok = myi < nE;
            int srcx = ok ? src : node;
            short8v v = *(const short8v*)&hw2[(size_t)srcx * 64 + gl * 8];
            if (ok) {
#pragma unroll
                for (int j = 0; j < 8; ++j) acc[j] += bf2f((unsigned short)v[j]);
            }
        }
    }
#pragma unroll
    for (int off = 8; off <= 32; off <<= 1) {
#pragma unroll
        for (int j = 0; j < 8; ++j) acc[j] += __shfl_xor(acc[j], off, 64);
    }
    short8v sv = *(const short8v*)&hw2[(size_t)node * 64 + gl * 8];
#pragma unroll
    for (int j = 0; j < 8; ++j) acc[j] += bf2f((unsigned short)sv[j]);

    float di = dinv[node];
    float4 b0 = *(const float4*)&b[gl * 8];
    float4 b1 = *(const float4*)&b[gl * 8 + 4];
    float val[8];
    val[0] = di * acc[0] + b0.x;
    val[1] = di * acc[1] + b0.y;
    val[2] = di * acc[2] + b0.z;
    val[3] = di * acc[3] + b0.w;
    val[4] = di * acc[4] + b1.x;
    val[5] = di * acc[5] + b1.y;
    val[6] = di * acc[6] + b1.z;
    val[7] = di * acc[7] + b1.w;

    float sq = 0.f;
#pragma unroll
    for (int j = 0; j < 8; ++j) sq += val[j] * val[j];
#pragma unroll
    for (int off = 1; off <= 4; off <<= 1) sq += __shfl_xor(sq, off, 64);
    float inv = 1.0f / fmaxf(sqrtf(sq), 1e-12f);

    if (grp == 0) {
        float4 r0, r1;
        r0.x = fmaxf(val[0] * inv, 0.f);
        r0.y = fmaxf(val[1] * inv, 0.f);
        r0.z = fmaxf(val[2] * inv, 0.f);
        r0.w = fmaxf(val[3] * inv, 0.f);
        r1.x = fmaxf(val[4] * inv, 0.f);
        r1.y = fmaxf(val[5] * inv, 0.f);
        r1.z = fmaxf(val[6] * inv, 0.f);
        r1.w = fmaxf(val[7] * inv, 0.f);
        *(float4*)&sh[tid >> 6][gl * 8] = r0;
        *(float4*)&sh[tid >> 6][gl * 8 + 4] = r1;
    }
    __syncthreads();
    if (tid < 64) {
        int nb = blockIdx.x * 4;
        int gcur = batch[nb];
        float runsum = 0.f, runmax = 0.f;
#pragma unroll
        for (int w = 0; w < 4; ++w) {
            int g = batch[nb + w];
            if (g != gcur) {
                atomicAdd(&gsum[gcur * 64 + tid], runsum);
                atomicMax((int*)&gmax[gcur * 64 + tid], __float_as_int(runmax));
                runsum = 0.f; runmax = 0.f; gcur = g;
            }
            float v = sh[w][tid];
            runsum += v;
            runmax = fmaxf(runmax, v);
        }
        atomicAdd(&gsum[gcur * 64 + tid], runsum);
        atomicMax((int*)&gmax[gcur * 64 + tid], __float_as_int(runmax));
    }
}

// Phase-2: one block per graph; mean + concat + 128x32 linear.
__global__ __launch_bounds__(128) void linear_kernel(const float* __restrict__ gsum,
                                                     const float* __restrict__ gmax,
                                                     const int* __restrict__ gstart,
                                                     const float* __restrict__ Wl,
                                                     const float* __restrict__ bl,
                                                     float* __restrict__ out) {
    int g = blockIdx.x;
    __shared__ float pooled[128];
    int t = threadIdx.x;
    if (t < 64) {
        int cnt = gstart[g + 1] - gstart[g];
        pooled[t] = gsum[g * 64 + t] / fmaxf((float)cnt, 1.0f);
    } else {
        pooled[t] = gmax[g * 64 + (t - 64)];
    }
    __syncthreads();
    if (t < 32) {
        float acc = bl[t];
#pragma unroll 8
        for (int k = 0; k < 128; ++k) acc += pooled[k] * Wl[k * 32 + t];
        out[g * 32 + t] = acc;
    }
}

extern "C" void kernel_launch(void* const* d_in, const int* in_sizes, int n_in,
                              void* d_out, int out_size, void* d_ws, size_t ws_size,
                              hipStream_t stream) {
    const float* x        = (const float*)d_in[0];   // 50000 x 128
    const int*   ei       = (const int*)d_in[1];     // 2 x 800000
    const int*   batch    = (const int*)d_in[2];     // 50000
    const float* W1       = (const float*)d_in[3];   // 128 x 64
    const float* b1       = (const float*)d_in[4];
    const float* W2       = (const float*)d_in[5];   // 64 x 64
    const float* b2       = (const float*)d_in[6];
    const float* W3       = (const float*)d_in[7];   // 64 x 64
    const float* b3       = (const float*)d_in[8];
    const float* Wl       = (const float*)d_in[9];   // 128 x 32
    const float* bl       = (const float*)d_in[10];
    float* out = (float*)d_out;

    char* ws = (char*)d_ws;
    int*   cnt      = (int*)ws;                 ws += align256((size_t)N_NODES * 4);
    int*   incl     = (int*)ws;                 ws += align256((size_t)N_NODES * 4);
    int*   bsum     = (int*)ws;                 ws += align256((size_t)SCAN_NB * 4);
    int*   boff     = (int*)ws;                 ws += align256((size_t)SCAN_NB * 4);
    int*   row_ptr  = (int*)ws;                 ws += align256((size_t)(N_NODES + 1) * 4);
    int*   fill_ptr = (int*)ws;                 ws += align256((size_t)N_NODES * 4);
    float* dinv     = (float*)ws;               ws += align256((size_t)N_NODES * 4);
    int*   gstart   = (int*)ws;                 ws += align256((size_t)(N_GRAPHS + 1) * 4);
    float* gsum     = (float*)ws;               ws += (size_t)N_GRAPHS * 64 * 4;   // contiguous
    float* gmax     = (float*)ws;               ws += align256((size_t)N_GRAPHS * 64 * 4);
    unsigned short* csr_src = (unsigned short*)ws; ws += align256((size_t)N_EDGES * 2);
    unsigned short* hwa = (unsigned short*)ws;  ws += align256((size_t)N_NODES * 64 * 2);
    unsigned short* hwb = (unsigned short*)ws;  ws += align256((size_t)N_NODES * 64 * 2);

    hipLaunchKernelGGL(zero2, dim3((N_NODES + 2 * N_GRAPHS * 64 + 255) / 256), dim3(256), 0,
                       stream, cnt, N_NODES, (int*)gsum, 2 * N_GRAPHS * 64);
    hipLaunchKernelGGL(deg_kernel, dim3((N_EDGES + 255) / 256), dim3(256), 0, stream, ei, cnt);
    hipLaunchKernelGGL(scan_a, dim3(SCAN_NB), dim3(256), 0, stream, cnt, incl, bsum);
    hipLaunchKernelGGL(scan_b_gstart, dim3(1), dim3(384), 0, stream, bsum, boff, batch, gstart);
    hipLaunchKernelGGL(scan_c, dim3(SCAN_NB), dim3(256), 0, stream,
                       cnt, incl, boff, row_ptr, fill_ptr, dinv);

    // fill (CSR scatter, u16, nontemporal ei) and layer-1 matmul overlap
    hipLaunchKernelGGL(fill_mm1_kernel, dim3(MM1_BLOCKS + FILL_BLOCKS), dim3(256), 0, stream,
                       ei, fill_ptr, csr_src, x, W1, dinv, hwa);

    const int aggmm_grid = N_NODES / 16;   // 3125, exact
    const int aggp_grid  = N_NODES / 4;    // 12500, exact

    // layer-1 agg + fused W2 matmul -> hwb
    hipLaunchKernelGGL(aggmm_kernel, dim3(aggmm_grid), dim3(1024), 0, stream,
                       hwa, row_ptr, csr_src, dinv, b1, W2, hwb);
    // layer-2 agg + fused W3 matmul -> hwa
    hipLaunchKernelGGL(aggmm_kernel, dim3(aggmm_grid), dim3(1024), 0, stream,
                       hwb, row_ptr, csr_src, dinv, b2, W3, hwa);
    // layer-3 agg + fused pooling
    hipLaunchKernelGGL(agg_pool_kernel, dim3(aggp_grid), dim3(256), 0, stream,
                       hwa, row_ptr, csr_src, dinv, b3, batch, gsum, gmax);

    // final linear
    hipLaunchKernelGGL(linear_kernel, dim3(N_GRAPHS), dim3(128), 0, stream,
                       gsum, gmax, gstart, Wl, bl, out);
}

// Round 21
// 205.827 us; speedup vs baseline: 1.0567x; 1.0567x over previous
//
#include <hip/hip_runtime.h>
#include <hip/hip_bf16.h>

#define N_NODES 50000
#define N_EDGES 800000
#define N_GRAPHS 64
#define HID 64
#define SCAN_NB 196  // ceil(50000/256)
#define FILL_RANGES 8
#define RANGE_SIZE ((N_NODES + FILL_RANGES - 1) / FILL_RANGES)  // 6250
#define MM1_BLOCKS ((N_NODES + 63) / 64)                        // 782
#define FILL_CHUNKS ((N_EDGES + 1023) / 1024)                   // 782
#define FILL_BLOCKS (FILL_RANGES * FILL_CHUNKS)                 // 6256

static inline size_t align256(size_t x) { return (x + 255) & ~(size_t)255; }

typedef __attribute__((ext_vector_type(8))) short short8v;
typedef __attribute__((ext_vector_type(4))) float f32x4;

// bf16 helpers (bit-level, RNE) -- storage compression + MFMA input prep.
__device__ __forceinline__ unsigned short f2bf(float f) {
    unsigned int u = __float_as_uint(f);
    unsigned int r = (u + 0x7fffu + ((u >> 16) & 1u)) >> 16;
    return (unsigned short)r;
}
__device__ __forceinline__ float bf2f(unsigned short h) {
    return __uint_as_float(((unsigned int)h) << 16);
}

// zero two disjoint int ranges in one launch (cnt | gsum+gmax)
__global__ void zero2(int* __restrict__ a, int na, int* __restrict__ b, int nb) {
    int i = blockIdx.x * blockDim.x + threadIdx.x;
    if (i < na) a[i] = 0;
    else if (i < na + nb) b[i - na] = 0;
}

// count incoming edges per destination node
// (round-20 lesson: NO nontemporal here -- ei is re-read 8x by fill; the
// hint forced L3/HBM refetches and cost +10us)
__global__ void deg_kernel(const int* __restrict__ ei, int* __restrict__ cnt) {
    int e = blockIdx.x * blockDim.x + threadIdx.x;
    if (e < N_EDGES) atomicAdd(&cnt[ei[N_EDGES + e]], 1);
}

// phase A: per-block (256-wide) inclusive scan of cnt; block totals to bsum
// (round-17 lesson: decoupled-lookback single-kernel scan serializes through
// a device-atomic chain, +14us; the 3 tiny grid-parallel launches win)
__global__ __launch_bounds__(256) void scan_a(const int* __restrict__ cnt,
                                              int* __restrict__ incl,
                                              int* __restrict__ bsum) {
    __shared__ int sd[256];
    int t = threadIdx.x;
    int i = blockIdx.x * 256 + t;
    int v = (i < N_NODES) ? cnt[i] : 0;
    sd[t] = v;
    __syncthreads();
    for (int off = 1; off < 256; off <<= 1) {
        int u = (t >= off) ? sd[t - off] : 0;
        __syncthreads();
        sd[t] += u;
        __syncthreads();
    }
    if (i < N_NODES) incl[i] = sd[t];
    if (t == 255) bsum[blockIdx.x] = sd[255];
}

// phase B (+gstart fused): threads 0..255 scan the block sums; threads
// 256..320 binary-search gstart (batch sorted). All threads hit every barrier.
__global__ __launch_bounds__(384) void scan_b_gstart(const int* __restrict__ bsum,
                                                     int* __restrict__ boff,
                                                     const int* __restrict__ batch,
                                                     int* __restrict__ gstart) {
    __shared__ int sd[256];
    int t = threadIdx.x;
    int v = 0;
    if (t < 256) {
        v = (t < SCAN_NB) ? bsum[t] : 0;
        sd[t] = v;
    }
    __syncthreads();
    for (int off = 1; off < 256; off <<= 1) {
        int u = (t < 256 && t >= off) ? sd[t - off] : 0;
        __syncthreads();
        if (t < 256) sd[t] += u;
        __syncthreads();
    }
    if (t < SCAN_NB) boff[t] = sd[t] - v;  // exclusive
    if (t >= 256 && t - 256 <= N_GRAPHS) {
        int g = t - 256;
        int lo = 0, hi = N_NODES;
        while (lo < hi) {
            int mid = (lo + hi) >> 1;
            if (batch[mid] < g) lo = mid + 1; else hi = mid;
        }
        gstart[g] = lo;
    }
}

// phase C: writeback row_ptr / fill_ptr / dinv
__global__ void scan_c(const int* __restrict__ cnt, const int* __restrict__ incl,
                       const int* __restrict__ boff, int* __restrict__ row_ptr,
                       int* __restrict__ fill_ptr, float* __restrict__ dinv) {
    int i = blockIdx.x * blockDim.x + threadIdx.x;
    if (i < N_NODES) {
        int c = cnt[i];
        int run = boff[i >> 8] + incl[i];  // inclusive prefix over all nodes
        row_ptr[i + 1] = run;
        fill_ptr[i] = run - c;             // bucket start
        dinv[i] = rsqrtf((float)c + 1.0f);
        if (i == 0) row_ptr[0] = 0;
    }
}

// DUAL-ROLE kernel: blocks [0, MM1_BLOCKS) run the layer-1 MFMA matmul;
// blocks [MM1_BLOCKS, ...) run the XCD-partitioned CSR scatter (round-8:
// one csr region written from one XCD; class (bid-MM1_BLOCKS)&7 is a fixed
// bid%8 residue). csr_src is uint16. Round-20: fill role widened to 4
// edges/thread via one int4 dst load (N_EDGES%4==0 -> aligned, no tail
// within a valid thread): 4x fewer fill blocks + 4x fewer load issues.
// Plain (cached) loads -- ei dst is re-read 8x across range classes and
// needs L2 residency (nontemporal regressed -10us, round 20).
// MM part: hw2 = bf16(dinv * (x @ W1)), 3-term hi/lo bf16 split; W fragments
// pre-swizzled in LDS; D layout (m89): row=(l>>4)*4+j, col=l&15.
__global__ __launch_bounds__(256) void fill_mm1_kernel(const int* __restrict__ ei,
                                                       int* __restrict__ fill_ptr,
                                                       unsigned short* __restrict__ csr_src,
                                                       const float* __restrict__ h,
                                                       const float* __restrict__ W,
                                                       const float* __restrict__ dinv,
                                                       unsigned short* __restrict__ hw2) {
    constexpr int K = 128;
    constexpr int NSTEP = K / 32;
    __shared__ unsigned short sWH[NSTEP * 4 * 64 * 8];
    __shared__ unsigned short sWL[NSTEP * 4 * 64 * 8];
    int tid = threadIdx.x;

    if (blockIdx.x >= MM1_BLOCKS) {
        // ---- fill role: 1024 edges per block, 4 per thread ----
        int fb = blockIdx.x - MM1_BLOCKS;
        int r = fb & (FILL_RANGES - 1);
        int ebase = (fb >> 3) * 1024 + tid * 4;
        if (ebase >= N_EDGES) return;          // full int4 valid when in-range
        int4 d4 = *(const int4*)&ei[N_EDGES + ebase];
        int lo = r * RANGE_SIZE;
        int hi = lo + RANGE_SIZE;
        int dsts[4] = {d4.x, d4.y, d4.z, d4.w};
#pragma unroll
        for (int j = 0; j < 4; ++j) {
            int dst = dsts[j];
            if (dst >= lo && dst < hi) {
                int src = ei[ebase + j];
                int pos = atomicAdd(&fill_ptr[dst], 1);
                csr_src[pos] = (unsigned short)src;
            }
        }
        return;
    }

    // ---- mm role ----
    int r0 = blockIdx.x * 64;
#pragma unroll 1
    for (int ent = tid; ent < NSTEP * 4 * 64; ent += 256) {
        int lane_e = ent & 63;
        int c = (ent >> 6) & 3;
        int step = ent >> 8;
        int kb = step * 32 + (lane_e >> 4) * 8;
        int n = c * 16 + (lane_e & 15);
#pragma unroll
        for (int j = 0; j < 8; ++j) {
            float f = W[(kb + j) * 64 + n];
            unsigned short hi = f2bf(f);
            sWH[ent * 8 + j] = hi;
            sWL[ent * 8 + j] = f2bf(f - bf2f(hi));
        }
    }
    __syncthreads();

    int lane = tid & 63;
    int wid = tid >> 6;
    int arow = min(r0 + wid * 16 + (lane & 15), N_NODES - 1);  // clamp; write guarded
    const float* ap = h + (size_t)arow * K;
    int klane = (lane >> 4) * 8;

    f32x4 acc[4];
#pragma unroll
    for (int c = 0; c < 4; ++c) acc[c] = (f32x4){0.f, 0.f, 0.f, 0.f};

#pragma unroll 1
    for (int step = 0; step < NSTEP; ++step) {
        int kb = step * 32 + klane;
        float4 f0 = *(const float4*)&ap[kb];
        float4 f1 = *(const float4*)&ap[kb + 4];
        float fv[8] = {f0.x, f0.y, f0.z, f0.w, f1.x, f1.y, f1.z, f1.w};
        short8v ahi, alo;
#pragma unroll
        for (int j = 0; j < 8; ++j) {
            unsigned short hi = f2bf(fv[j]);
            ahi[j] = (short)hi;
            alo[j] = (short)f2bf(fv[j] - bf2f(hi));
        }
#pragma unroll
        for (int c = 0; c < 4; ++c) {
            short8v bh = *(const short8v*)&sWH[((step * 4 + c) * 64 + lane) * 8];
            short8v bl = *(const short8v*)&sWL[((step * 4 + c) * 64 + lane) * 8];
            acc[c] = __builtin_amdgcn_mfma_f32_16x16x32_bf16(ahi, bh, acc[c], 0, 0, 0);
            acc[c] = __builtin_amdgcn_mfma_f32_16x16x32_bf16(alo, bh, acc[c], 0, 0, 0);
            acc[c] = __builtin_amdgcn_mfma_f32_16x16x32_bf16(ahi, bl, acc[c], 0, 0, 0);
        }
    }

    int rb = r0 + wid * 16 + (lane >> 4) * 4;
#pragma unroll
    for (int j = 0; j < 4; ++j) {
        int row = rb + j;
        if (row < N_NODES) {
            float dv = dinv[row];
#pragma unroll
            for (int c = 0; c < 4; ++c) {
                hw2[(size_t)row * 64 + c * 16 + (lane & 15)] = f2bf(dv * acc[c][j]);
            }
        }
    }
}

// FUSED agg + next-layer MFMA matmul. 1024 threads = 16 waves = 16 nodes
// (50000 = 3125*16 exact, no tail -> barrier-safe). Gather 8-wide
// MLP-unrolled (round-14/16); wave-uniform shfl (round-5). Waves deposit
// normalized h rows into a 16x68-padded LDS tile, barrier, waves 0-3 each
// compute one 16-col tile of h @ Wn via the same 3-term hi/lo MFMA as the
// standalone mm64 (bit-identical arithmetic).
__global__ __launch_bounds__(1024) void aggmm_kernel(const unsigned short* __restrict__ hw_in,
                                                     const int* __restrict__ row_ptr,
                                                     const unsigned short* __restrict__ csr_src,
                                                     const float* __restrict__ dinv,
                                                     const float* __restrict__ b,
                                                     const float* __restrict__ Wn,
                                                     unsigned short* __restrict__ hw_out) {
    __shared__ unsigned short sWH[2 * 4 * 64 * 8];  // 8 KB
    __shared__ unsigned short sWL[2 * 4 * 64 * 8];  // 8 KB
    __shared__ float hlds[16 * 68];                 // padded stride 68
    int tid = threadIdx.x;

    if (tid < 512) {
        int ent = tid;
        int lane_e = ent & 63;
        int c = (ent >> 6) & 3;
        int step = ent >> 8;
        int kb = step * 32 + (lane_e >> 4) * 8;
        int n = c * 16 + (lane_e & 15);
#pragma unroll
        for (int j = 0; j < 8; ++j) {
            float f = Wn[(kb + j) * 64 + n];
            unsigned short hi = f2bf(f);
            sWH[ent * 8 + j] = hi;
            sWL[ent * 8 + j] = f2bf(f - bf2f(hi));
        }
    }

    int wid = tid >> 6;
    int node = blockIdx.x * 16 + wid;
    int lane = tid & 63;
    int grp = lane >> 3;
    int gl  = lane & 7;
    int s = row_ptr[node], e = row_ptr[node + 1];

    float acc[8] = {0.f, 0.f, 0.f, 0.f, 0.f, 0.f, 0.f, 0.f};
    for (int base = s; base < e; base += 64) {
        int nE = min(64, e - base);
        int msrc = (lane < nE) ? (int)csr_src[base + lane] : 0;
#pragma unroll
        for (int rr = 0; rr < 8; ++rr) {
            int i = rr * 8;
            if (i >= nE) break;
            int myi = i + grp;
            int src = __shfl(msrc, myi, 64);
            bool ok = myi < nE;
            int srcx = ok ? src : node;
            short8v v = *(const short8v*)&hw_in[(size_t)srcx * 64 + gl * 8];
            if (ok) {
#pragma unroll
                for (int j = 0; j < 8; ++j) acc[j] += bf2f((unsigned short)v[j]);
            }
        }
    }
#pragma unroll
    for (int off = 8; off <= 32; off <<= 1) {
#pragma unroll
        for (int j = 0; j < 8; ++j) acc[j] += __shfl_xor(acc[j], off, 64);
    }
    short8v sv = *(const short8v*)&hw_in[(size_t)node * 64 + gl * 8];
#pragma unroll
    for (int j = 0; j < 8; ++j) acc[j] += bf2f((unsigned short)sv[j]);

    float di = dinv[node];
    float4 b0 = *(const float4*)&b[gl * 8];
    float4 b1 = *(const float4*)&b[gl * 8 + 4];
    float val[8];
    val[0] = di * acc[0] + b0.x;
    val[1] = di * acc[1] + b0.y;
    val[2] = di * acc[2] + b0.z;
    val[3] = di * acc[3] + b0.w;
    val[4] = di * acc[4] + b1.x;
    val[5] = di * acc[5] + b1.y;
    val[6] = di * acc[6] + b1.z;
    val[7] = di * acc[7] + b1.w;

    float sq = 0.f;
#pragma unroll
    for (int j = 0; j < 8; ++j) sq += val[j] * val[j];
#pragma unroll
    for (int off = 1; off <= 4; off <<= 1) sq += __shfl_xor(sq, off, 64);
    float inv = 1.0f / fmaxf(sqrtf(sq), 1e-12f);

    if (grp == 0) {
        float4 r0, r1;
        r0.x = fmaxf(val[0] * inv, 0.f);
        r0.y = fmaxf(val[1] * inv, 0.f);
        r0.z = fmaxf(val[2] * inv, 0.f);
        r0.w = fmaxf(val[3] * inv, 0.f);
        r1.x = fmaxf(val[4] * inv, 0.f);
        r1.y = fmaxf(val[5] * inv, 0.f);
        r1.z = fmaxf(val[6] * inv, 0.f);
        r1.w = fmaxf(val[7] * inv, 0.f);
        *(float4*)&hlds[wid * 68 + gl * 8] = r0;
        *(float4*)&hlds[wid * 68 + gl * 8 + 4] = r1;
    }
    __syncthreads();

    if (wid < 4) {
        int klane = (lane >> 4) * 8;
        f32x4 macc = (f32x4){0.f, 0.f, 0.f, 0.f};
#pragma unroll
        for (int step = 0; step < 2; ++step) {
            const float* hr = &hlds[(lane & 15) * 68 + step * 32 + klane];
            short8v ahi, alo;
#pragma unroll
            for (int j = 0; j < 8; ++j) {
                float f = hr[j];
                unsigned short hi = f2bf(f);
                ahi[j] = (short)hi;
                alo[j] = (short)f2bf(f - bf2f(hi));
            }
            short8v bh = *(const short8v*)&sWH[((step * 4 + wid) * 64 + lane) * 8];
            short8v bl = *(const short8v*)&sWL[((step * 4 + wid) * 64 + lane) * 8];
            macc = __builtin_amdgcn_mfma_f32_16x16x32_bf16(ahi, bh, macc, 0, 0, 0);
            macc = __builtin_amdgcn_mfma_f32_16x16x32_bf16(alo, bh, macc, 0, 0, 0);
            macc = __builtin_amdgcn_mfma_f32_16x16x32_bf16(ahi, bl, macc, 0, 0, 0);
        }
        int rb = blockIdx.x * 16 + (lane >> 4) * 4;
#pragma unroll
        for (int j = 0; j < 4; ++j) {
            int row = rb + j;
            hw_out[(size_t)row * 64 + wid * 16 + (lane & 15)] = f2bf(dinv[row] * macc[j]);
        }
    }
}

// Final agg (layer 3) + fused pooling: 256 threads, 4 nodes/block (grid
// exact N_NODES/4). Block's 4 rows -> LDS, 64 threads run-combine per dim
// (batch sorted), ~1 atomicAdd+atomicMax per dim/block.
__global__ __launch_bounds__(256) void agg_pool_kernel(const unsigned short* __restrict__ hw2,
                                                       const int* __restrict__ row_ptr,
                                                       const unsigned short* __restrict__ csr_src,
                                                       const float* __restrict__ dinv,
                                                       const float* __restrict__ b,
                                                       const int* __restrict__ batch,
                                                       float* __restrict__ gsum,
                                                       float* __restrict__ gmax) {
    __shared__ float sh[4][64];
    int tid = threadIdx.x;
    int node = blockIdx.x * 4 + (tid >> 6);
    int lane = tid & 63;
    int grp = lane >> 3;
    int gl  = lane & 7;
    int s = row_ptr[node], e = row_ptr[node + 1];

    float acc[8] = {0.f, 0.f, 0.f, 0.f, 0.f, 0.f, 0.f, 0.f};
    for (int base = s; base < e; base += 64) {
        int nE = min(64, e - base);
        int msrc = (lane < nE) ? (int)csr_src[base + lane] : 0;
#pragma unroll
        for (int rr = 0; rr < 8; ++rr) {
            int i = rr * 8;
            if (i >= nE) break;
            int myi = i + grp;
            int src = __shfl(msrc, myi, 64);
            bool ok = myi < nE;
            int srcx = ok ? src : node;
            short8v v = *(const short8v*)&hw2[(size_t)srcx * 64 + gl * 8];
            if (ok) {
#pragma unroll
                for (int j = 0; j < 8; ++j) acc[j] += bf2f((unsigned short)v[j]);
            }
        }
    }
#pragma unroll
    for (int off = 8; off <= 32; off <<= 1) {
#pragma unroll
        for (int j = 0; j < 8; ++j) acc[j] += __shfl_xor(acc[j], off, 64);
    }
    short8v sv = *(const short8v*)&hw2[(size_t)node * 64 + gl * 8];
#pragma unroll
    for (int j = 0; j < 8; ++j) acc[j] += bf2f((unsigned short)sv[j]);

    float di = dinv[node];
    float4 b0 = *(const float4*)&b[gl * 8];
    float4 b1 = *(const float4*)&b[gl * 8 + 4];
    float val[8];
    val[0] = di * acc[0] + b0.x;
    val[1] = di * acc[1] + b0.y;
    val[2] = di * acc[2] + b0.z;
    val[3] = di * acc[3] + b0.w;
    val[4] = di * acc[4] + b1.x;
    val[5] = di * acc[5] + b1.y;
    val[6] = di * acc[6] + b1.z;
    val[7] = di * acc[7] + b1.w;

    float sq = 0.f;
#pragma unroll
    for (int j = 0; j < 8; ++j) sq += val[j] * val[j];
#pragma unroll
    for (int off = 1; off <= 4; off <<= 1) sq += __shfl_xor(sq, off, 64);
    float inv = 1.0f / fmaxf(sqrtf(sq), 1e-12f);

    if (grp == 0) {
        float4 r0, r1;
        r0.x = fmaxf(val[0] * inv, 0.f);
        r0.y = fmaxf(val[1] * inv, 0.f);
        r0.z = fmaxf(val[2] * inv, 0.f);
        r0.w = fmaxf(val[3] * inv, 0.f);
        r1.x = fmaxf(val[4] * inv, 0.f);
        r1.y = fmaxf(val[5] * inv, 0.f);
        r1.z = fmaxf(val[6] * inv, 0.f);
        r1.w = fmaxf(val[7] * inv, 0.f);
        *(float4*)&sh[tid >> 6][gl * 8] = r0;
        *(float4*)&sh[tid >> 6][gl * 8 + 4] = r1;
    }
    __syncthreads();
    if (tid < 64) {
        int nb = blockIdx.x * 4;
        int gcur = batch[nb];
        float runsum = 0.f, runmax = 0.f;
#pragma unroll
        for (int w = 0; w < 4; ++w) {
            int g = batch[nb + w];
            if (g != gcur) {
                atomicAdd(&gsum[gcur * 64 + tid], runsum);
                atomicMax((int*)&gmax[gcur * 64 + tid], __float_as_int(runmax));
                runsum = 0.f; runmax = 0.f; gcur = g;
            }
            float v = sh[w][tid];
            runsum += v;
            runmax = fmaxf(runmax, v);
        }
        atomicAdd(&gsum[gcur * 64 + tid], runsum);
        atomicMax((int*)&gmax[gcur * 64 + tid], __float_as_int(runmax));
    }
}

// Phase-2: one block per graph; mean + concat + 128x32 linear.
__global__ __launch_bounds__(128) void linear_kernel(const float* __restrict__ gsum,
                                                     const float* __restrict__ gmax,
                                                     const int* __restrict__ gstart,
                                                     const float* __restrict__ Wl,
                                                     const float* __restrict__ bl,
                                                     float* __restrict__ out) {
    int g = blockIdx.x;
    __shared__ float pooled[128];
    int t = threadIdx.x;
    if (t < 64) {
        int cnt = gstart[g + 1] - gstart[g];
        pooled[t] = gsum[g * 64 + t] / fmaxf((float)cnt, 1.0f);
    } else {
        pooled[t] = gmax[g * 64 + (t - 64)];
    }
    __syncthreads();
    if (t < 32) {
        float acc = bl[t];
#pragma unroll 8
        for (int k = 0; k < 128; ++k) acc += pooled[k] * Wl[k * 32 + t];
        out[g * 32 + t] = acc;
    }
}

extern "C" void kernel_launch(void* const* d_in, const int* in_sizes, int n_in,
                              void* d_out, int out_size, void* d_ws, size_t ws_size,
                              hipStream_t stream) {
    const float* x        = (const float*)d_in[0];   // 50000 x 128
    const int*   ei       = (const int*)d_in[1];     // 2 x 800000
    const int*   batch    = (const int*)d_in[2];     // 50000
    const float* W1       = (const float*)d_in[3];   // 128 x 64
    const float* b1       = (const float*)d_in[4];
    const float* W2       = (const float*)d_in[5];   // 64 x 64
    const float* b2       = (const float*)d_in[6];
    const float* W3       = (const float*)d_in[7];   // 64 x 64
    const float* b3       = (const float*)d_in[8];
    const float* Wl       = (const float*)d_in[9];   // 128 x 32
    const float* bl       = (const float*)d_in[10];
    float* out = (float*)d_out;

    char* ws = (char*)d_ws;
    int*   cnt      = (int*)ws;                 ws += align256((size_t)N_NODES * 4);
    int*   incl     = (int*)ws;                 ws += align256((size_t)N_NODES * 4);
    int*   bsum     = (int*)ws;                 ws += align256((size_t)SCAN_NB * 4);
    int*   boff     = (int*)ws;                 ws += align256((size_t)SCAN_NB * 4);
    int*   row_ptr  = (int*)ws;                 ws += align256((size_t)(N_NODES + 1) * 4);
    int*   fill_ptr = (int*)ws;                 ws += align256((size_t)N_NODES * 4);
    float* dinv     = (float*)ws;               ws += align256((size_t)N_NODES * 4);
    int*   gstart   = (int*)ws;                 ws += align256((size_t)(N_GRAPHS + 1) * 4);
    float* gsum     = (float*)ws;               ws += (size_t)N_GRAPHS * 64 * 4;   // contiguous
    float* gmax     = (float*)ws;               ws += align256((size_t)N_GRAPHS * 64 * 4);
    unsigned short* csr_src = (unsigned short*)ws; ws += align256((size_t)N_EDGES * 2);
    unsigned short* hwa = (unsigned short*)ws;  ws += align256((size_t)N_NODES * 64 * 2);
    unsigned short* hwb = (unsigned short*)ws;  ws += align256((size_t)N_NODES * 64 * 2);

    hipLaunchKernelGGL(zero2, dim3((N_NODES + 2 * N_GRAPHS * 64 + 255) / 256), dim3(256), 0,
                       stream, cnt, N_NODES, (int*)gsum, 2 * N_GRAPHS * 64);
    hipLaunchKernelGGL(deg_kernel, dim3((N_EDGES + 255) / 256), dim3(256), 0, stream, ei, cnt);
    hipLaunchKernelGGL(scan_a, dim3(SCAN_NB), dim3(256), 0, stream, cnt, incl, bsum);
    hipLaunchKernelGGL(scan_b_gstart, dim3(1), dim3(384), 0, stream, bsum, boff, batch, gstart);
    hipLaunchKernelGGL(scan_c, dim3(SCAN_NB), dim3(256), 0, stream,
                       cnt, incl, boff, row_ptr, fill_ptr, dinv);

    // fill (CSR scatter, u16, 4 edges/thread) and layer-1 matmul overlap
    hipLaunchKernelGGL(fill_mm1_kernel, dim3(MM1_BLOCKS + FILL_BLOCKS), dim3(256), 0, stream,
                       ei, fill_ptr, csr_src, x, W1, dinv, hwa);

    const int aggmm_grid = N_NODES / 16;   // 3125, exact
    const int aggp_grid  = N_NODES / 4;    // 12500, exact

    // layer-1 agg + fused W2 matmul -> hwb
    hipLaunchKernelGGL(aggmm_kernel, dim3(aggmm_grid), dim3(1024), 0, stream,
                       hwa, row_ptr, csr_src, dinv, b1, W2, hwb);
    // layer-2 agg + fused W3 matmul -> hwa
    hipLaunchKernelGGL(aggmm_kernel, dim3(aggmm_grid), dim3(1024), 0, stream,
                       hwb, row_ptr, csr_src, dinv, b2, W3, hwa);
    // layer-3 agg + fused pooling
    hipLaunchKernelGGL(agg_pool_kernel, dim3(aggp_grid), dim3(256), 0, stream,
                       hwa, row_ptr, csr_src, dinv, b3, batch, gsum, gmax);

    // final linear
    hipLaunchKernelGGL(linear_kernel, dim3(N_GRAPHS), dim3(128), 0, stream,
                       gsum, gmax, gstart, Wl, bl, out);
}

// Round 22
// 203.123 us; speedup vs baseline: 1.0708x; 1.0133x over previous
//
#include <hip/hip_runtime.h>
#include <hip/hip_bf16.h>

#define N_NODES 50000
#define N_EDGES 800000
#define N_GRAPHS 64
#define HID 64
#define SCAN_NB 196  // ceil(50000/256)
#define FILL_RANGES 8
#define RANGE_SIZE ((N_NODES + FILL_RANGES - 1) / FILL_RANGES)  // 6250
#define MM1_BLOCKS ((N_NODES + 63) / 64)                        // 782
#define FILL_CHUNKS ((N_EDGES + 1023) / 1024)                   // 782
#define FILL_BLOCKS (FILL_RANGES * FILL_CHUNKS)                 // 6256

static inline size_t align256(size_t x) { return (x + 255) & ~(size_t)255; }

typedef __attribute__((ext_vector_type(8))) short short8v;
typedef __attribute__((ext_vector_type(4))) float f32x4;

// bf16 helpers (bit-level, RNE) -- storage compression + MFMA input prep.
__device__ __forceinline__ unsigned short f2bf(float f) {
    unsigned int u = __float_as_uint(f);
    unsigned int r = (u + 0x7fffu + ((u >> 16) & 1u)) >> 16;
    return (unsigned short)r;
}
__device__ __forceinline__ float bf2f(unsigned short h) {
    return __uint_as_float(((unsigned int)h) << 16);
}

// zero two disjoint int ranges in one launch (cnt | gsum+gmax)
__global__ void zero2(int* __restrict__ a, int na, int* __restrict__ b, int nb) {
    int i = blockIdx.x * blockDim.x + threadIdx.x;
    if (i < na) a[i] = 0;
    else if (i < na + nb) b[i - na] = 0;
}

// count incoming edges per destination node
// (round-20 lesson: NO nontemporal -- ei is re-read 8x by fill)
__global__ void deg_kernel(const int* __restrict__ ei, int* __restrict__ cnt) {
    int e = blockIdx.x * blockDim.x + threadIdx.x;
    if (e < N_EDGES) atomicAdd(&cnt[ei[N_EDGES + e]], 1);
}

// phase A: per-block (256-wide) inclusive scan of cnt; block totals to bsum
// (round-17 lesson: decoupled-lookback scan serializes on a device-atomic
// chain, +14us; the 3 tiny grid-parallel launches win)
__global__ __launch_bounds__(256) void scan_a(const int* __restrict__ cnt,
                                              int* __restrict__ incl,
                                              int* __restrict__ bsum) {
    __shared__ int sd[256];
    int t = threadIdx.x;
    int i = blockIdx.x * 256 + t;
    int v = (i < N_NODES) ? cnt[i] : 0;
    sd[t] = v;
    __syncthreads();
    for (int off = 1; off < 256; off <<= 1) {
        int u = (t >= off) ? sd[t - off] : 0;
        __syncthreads();
        sd[t] += u;
        __syncthreads();
    }
    if (i < N_NODES) incl[i] = sd[t];
    if (t == 255) bsum[blockIdx.x] = sd[255];
}

// phase B (+gstart fused): threads 0..255 scan the block sums; threads
// 256..320 binary-search gstart (batch sorted). All threads hit every barrier.
__global__ __launch_bounds__(384) void scan_b_gstart(const int* __restrict__ bsum,
                                                     int* __restrict__ boff,
                                                     const int* __restrict__ batch,
                                                     int* __restrict__ gstart) {
    __shared__ int sd[256];
    int t = threadIdx.x;
    int v = 0;
    if (t < 256) {
        v = (t < SCAN_NB) ? bsum[t] : 0;
        sd[t] = v;
    }
    __syncthreads();
    for (int off = 1; off < 256; off <<= 1) {
        int u = (t < 256 && t >= off) ? sd[t - off] : 0;
        __syncthreads();
        if (t < 256) sd[t] += u;
        __syncthreads();
    }
    if (t < SCAN_NB) boff[t] = sd[t] - v;  // exclusive
    if (t >= 256 && t - 256 <= N_GRAPHS) {
        int g = t - 256;
        int lo = 0, hi = N_NODES;
        while (lo < hi) {
            int mid = (lo + hi) >> 1;
            if (batch[mid] < g) lo = mid + 1; else hi = mid;
        }
        gstart[g] = lo;
    }
}

// phase C: writeback row_ptr / fill_ptr / dinv
__global__ void scan_c(const int* __restrict__ cnt, const int* __restrict__ incl,
                       const int* __restrict__ boff, int* __restrict__ row_ptr,
                       int* __restrict__ fill_ptr, float* __restrict__ dinv) {
    int i = blockIdx.x * blockDim.x + threadIdx.x;
    if (i < N_NODES) {
        int c = cnt[i];
        int run = boff[i >> 8] + incl[i];  // inclusive prefix over all nodes
        row_ptr[i + 1] = run;
        fill_ptr[i] = run - c;             // bucket start
        dinv[i] = rsqrtf((float)c + 1.0f);
        if (i == 0) row_ptr[0] = 0;
    }
}

// DUAL-ROLE kernel: blocks [0, MM1_BLOCKS) run the layer-1 MFMA matmul;
// blocks [MM1_BLOCKS, ...) run the XCD-partitioned CSR scatter (round-8:
// one csr region written from one XCD; class fb&7 maps to a fixed XCD).
// csr_src is uint16; fill is 4 edges/thread via one int4 dst load (round-21).
// ROUND-22: W staged PER K-STEP (4KB hi + 4KB lo, re-staged in the NSTEP
// loop) instead of whole (32KB) -- static LDS was capping the WHOLE kernel
// (including the 6256 LDS-free fill blocks) at 5 blocks/CU (36% occupancy,
// latency-bound fill). 8KB -> waves-bound 8 blocks/CU.
// MM: hw2 = bf16(dinv*(x@W1)), 3-term hi/lo bf16 split; D layout (m89):
// row=(l>>4)*4+j, col=l&15.
__global__ __launch_bounds__(256) void fill_mm1_kernel(const int* __restrict__ ei,
                                                       int* __restrict__ fill_ptr,
                                                       unsigned short* __restrict__ csr_src,
                                                       const float* __restrict__ h,
                                                       const float* __restrict__ W,
                                                       const float* __restrict__ dinv,
                                                       unsigned short* __restrict__ hw2) {
    constexpr int K = 128;
    constexpr int NSTEP = K / 32;
    __shared__ unsigned short sWH[4 * 64 * 8];  // 4 KB (one k-step)
    __shared__ unsigned short sWL[4 * 64 * 8];  // 4 KB
    int tid = threadIdx.x;

    if (blockIdx.x >= MM1_BLOCKS) {
        // ---- fill role: 1024 edges per block, 4 per thread ----
        int fb = blockIdx.x - MM1_BLOCKS;
        int r = fb & (FILL_RANGES - 1);
        int ebase = (fb >> 3) * 1024 + tid * 4;
        if (ebase >= N_EDGES) return;          // full int4 valid when in-range
        int4 d4 = *(const int4*)&ei[N_EDGES + ebase];
        int lo = r * RANGE_SIZE;
        int hi = lo + RANGE_SIZE;
        int dsts[4] = {d4.x, d4.y, d4.z, d4.w};
#pragma unroll
        for (int j = 0; j < 4; ++j) {
            int dst = dsts[j];
            if (dst >= lo && dst < hi) {
                int src = ei[ebase + j];
                int pos = atomicAdd(&fill_ptr[dst], 1);
                csr_src[pos] = (unsigned short)src;
            }
        }
        return;
    }

    // ---- mm role ----
    int r0 = blockIdx.x * 64;
    int lane = tid & 63;
    int wid = tid >> 6;
    int arow = min(r0 + wid * 16 + (lane & 15), N_NODES - 1);  // clamp; write guarded
    const float* ap = h + (size_t)arow * K;
    int klane = (lane >> 4) * 8;

    f32x4 acc[4];
#pragma unroll
    for (int c = 0; c < 4; ++c) acc[c] = (f32x4){0.f, 0.f, 0.f, 0.f};

#pragma unroll 1
    for (int step = 0; step < NSTEP; ++step) {
        // stage this step's W fragments: 256 entries, one per thread
        {
            int ent = tid;
            int lane_e = ent & 63;
            int c = (ent >> 6) & 3;
            int kb = step * 32 + (lane_e >> 4) * 8;
            int n = c * 16 + (lane_e & 15);
#pragma unroll
            for (int j = 0; j < 8; ++j) {
                float f = W[(kb + j) * 64 + n];
                unsigned short hi = f2bf(f);
                sWH[ent * 8 + j] = hi;
                sWL[ent * 8 + j] = f2bf(f - bf2f(hi));
            }
        }
        __syncthreads();

        int kb = step * 32 + klane;
        float4 f0 = *(const float4*)&ap[kb];
        float4 f1 = *(const float4*)&ap[kb + 4];
        float fv[8] = {f0.x, f0.y, f0.z, f0.w, f1.x, f1.y, f1.z, f1.w};
        short8v ahi, alo;
#pragma unroll
        for (int j = 0; j < 8; ++j) {
            unsigned short hi = f2bf(fv[j]);
            ahi[j] = (short)hi;
            alo[j] = (short)f2bf(fv[j] - bf2f(hi));
        }
#pragma unroll
        for (int c = 0; c < 4; ++c) {
            short8v bh = *(const short8v*)&sWH[(c * 64 + lane) * 8];
            short8v bl = *(const short8v*)&sWL[(c * 64 + lane) * 8];
            acc[c] = __builtin_amdgcn_mfma_f32_16x16x32_bf16(ahi, bh, acc[c], 0, 0, 0);
            acc[c] = __builtin_amdgcn_mfma_f32_16x16x32_bf16(alo, bh, acc[c], 0, 0, 0);
            acc[c] = __builtin_amdgcn_mfma_f32_16x16x32_bf16(ahi, bl, acc[c], 0, 0, 0);
        }
        __syncthreads();
    }

    int rb = r0 + wid * 16 + (lane >> 4) * 4;
#pragma unroll
    for (int j = 0; j < 4; ++j) {
        int row = rb + j;
        if (row < N_NODES) {
            float dv = dinv[row];
#pragma unroll
            for (int c = 0; c < 4; ++c) {
                hw2[(size_t)row * 64 + c * 16 + (lane & 15)] = f2bf(dv * acc[c][j]);
            }
        }
    }
}

// FUSED agg + next-layer MFMA matmul. 1024 threads = 16 waves = 16 nodes
// (50000 = 3125*16 exact, no tail -> barrier-safe). Gather 8-wide
// MLP-unrolled (round-14/16); wave-uniform shfl (round-5). Waves deposit
// normalized h rows into a 16x68-padded LDS tile, barrier, waves 0-3 each
// compute one 16-col tile of h @ Wn via the same 3-term hi/lo MFMA as the
// standalone mm64 (bit-identical arithmetic).
__global__ __launch_bounds__(1024) void aggmm_kernel(const unsigned short* __restrict__ hw_in,
                                                     const int* __restrict__ row_ptr,
                                                     const unsigned short* __restrict__ csr_src,
                                                     const float* __restrict__ dinv,
                                                     const float* __restrict__ b,
                                                     const float* __restrict__ Wn,
                                                     unsigned short* __restrict__ hw_out) {
    __shared__ unsigned short sWH[2 * 4 * 64 * 8];  // 8 KB
    __shared__ unsigned short sWL[2 * 4 * 64 * 8];  // 8 KB
    __shared__ float hlds[16 * 68];                 // padded stride 68
    int tid = threadIdx.x;

    if (tid < 512) {
        int ent = tid;
        int lane_e = ent & 63;
        int c = (ent >> 6) & 3;
        int step = ent >> 8;
        int kb = step * 32 + (lane_e >> 4) * 8;
        int n = c * 16 + (lane_e & 15);
#pragma unroll
        for (int j = 0; j < 8; ++j) {
            float f = Wn[(kb + j) * 64 + n];
            unsigned short hi = f2bf(f);
            sWH[ent * 8 + j] = hi;
            sWL[ent * 8 + j] = f2bf(f - bf2f(hi));
        }
    }

    int wid = tid >> 6;
    int node = blockIdx.x * 16 + wid;
    int lane = tid & 63;
    int grp = lane >> 3;
    int gl  = lane & 7;
    int s = row_ptr[node], e = row_ptr[node + 1];

    float acc[8] = {0.f, 0.f, 0.f, 0.f, 0.f, 0.f, 0.f, 0.f};
    for (int base = s; base < e; base += 64) {
        int nE = min(64, e - base);
        int msrc = (lane < nE) ? (int)csr_src[base + lane] : 0;
#pragma unroll
        for (int rr = 0; rr < 8; ++rr) {
            int i = rr * 8;
            if (i >= nE) break;
            int myi = i + grp;
            int src = __shfl(msrc, myi, 64);
            bool ok = myi < nE;
            int srcx = ok ? src : node;
            short8v v = *(const short8v*)&hw_in[(size_t)srcx * 64 + gl * 8];
            if (ok) {
#pragma unroll
                for (int j = 0; j < 8; ++j) acc[j] += bf2f((unsigned short)v[j]);
            }
        }
    }
#pragma unroll
    for (int off = 8; off <= 32; off <<= 1) {
#pragma unroll
        for (int j = 0; j < 8; ++j) acc[j] += __shfl_xor(acc[j], off, 64);
    }
    short8v sv = *(const short8v*)&hw_in[(size_t)node * 64 + gl * 8];
#pragma unroll
    for (int j = 0; j < 8; ++j) acc[j] += bf2f((unsigned short)sv[j]);

    float di = dinv[node];
    float4 b0 = *(const float4*)&b[gl * 8];
    float4 b1 = *(const float4*)&b[gl * 8 + 4];
    float val[8];
    val[0] = di * acc[0] + b0.x;
    val[1] = di * acc[1] + b0.y;
    val[2] = di * acc[2] + b0.z;
    val[3] = di * acc[3] + b0.w;
    val[4] = di * acc[4] + b1.x;
    val[5] = di * acc[5] + b1.y;
    val[6] = di * acc[6] + b1.z;
    val[7] = di * acc[7] + b1.w;

    float sq = 0.f;
#pragma unroll
    for (int j = 0; j < 8; ++j) sq += val[j] * val[j];
#pragma unroll
    for (int off = 1; off <= 4; off <<= 1) sq += __shfl_xor(sq, off, 64);
    float inv = 1.0f / fmaxf(sqrtf(sq), 1e-12f);

    if (grp == 0) {
        float4 r0, r1;
        r0.x = fmaxf(val[0] * inv, 0.f);
        r0.y = fmaxf(val[1] * inv, 0.f);
        r0.z = fmaxf(val[2] * inv, 0.f);
        r0.w = fmaxf(val[3] * inv, 0.f);
        r1.x = fmaxf(val[4] * inv, 0.f);
        r1.y = fmaxf(val[5] * inv, 0.f);
        r1.z = fmaxf(val[6] * inv, 0.f);
        r1.w = fmaxf(val[7] * inv, 0.f);
        *(float4*)&hlds[wid * 68 + gl * 8] = r0;
        *(float4*)&hlds[wid * 68 + gl * 8 + 4] = r1;
    }
    __syncthreads();

    if (wid < 4) {
        int klane = (lane >> 4) * 8;
        f32x4 macc = (f32x4){0.f, 0.f, 0.f, 0.f};
#pragma unroll
        for (int step = 0; step < 2; ++step) {
            const float* hr = &hlds[(lane & 15) * 68 + step * 32 + klane];
            short8v ahi, alo;
#pragma unroll
            for (int j = 0; j < 8; ++j) {
                float f = hr[j];
                unsigned short hi = f2bf(f);
                ahi[j] = (short)hi;
                alo[j] = (short)f2bf(f - bf2f(hi));
            }
            short8v bh = *(const short8v*)&sWH[((step * 4 + wid) * 64 + lane) * 8];
            short8v bl = *(const short8v*)&sWL[((step * 4 + wid) * 64 + lane) * 8];
            macc = __builtin_amdgcn_mfma_f32_16x16x32_bf16(ahi, bh, macc, 0, 0, 0);
            macc = __builtin_amdgcn_mfma_f32_16x16x32_bf16(alo, bh, macc, 0, 0, 0);
            macc = __builtin_amdgcn_mfma_f32_16x16x32_bf16(ahi, bl, macc, 0, 0, 0);
        }
        int rb = blockIdx.x * 16 + (lane >> 4) * 4;
#pragma unroll
        for (int j = 0; j < 4; ++j) {
            int row = rb + j;
            hw_out[(size_t)row * 64 + wid * 16 + (lane & 15)] = f2bf(dinv[row] * macc[j]);
        }
    }
}

// Final agg (layer 3) + fused pooling: 256 threads, 4 nodes/block (grid
// exact N_NODES/4). Block's 4 rows -> LDS, 64 threads run-combine per dim
// (batch sorted), ~1 atomicAdd+atomicMax per dim/block.
__global__ __launch_bounds__(256) void agg_pool_kernel(const unsigned short* __restrict__ hw2,
                                                       const int* __restrict__ row_ptr,
                                                       const unsigned short* __restrict__ csr_src,
                                                       const float* __restrict__ dinv,
                                                       const float* __restrict__ b,
                                                       const int* __restrict__ batch,
                                                       float* __restrict__ gsum,
                                                       float* __restrict__ gmax) {
    __shared__ float sh[4][64];
    int tid = threadIdx.x;
    int node = blockIdx.x * 4 + (tid >> 6);
    int lane = tid & 63;
    int grp = lane >> 3;
    int gl  = lane & 7;
    int s = row_ptr[node], e = row_ptr[node + 1];

    float acc[8] = {0.f, 0.f, 0.f, 0.f, 0.f, 0.f, 0.f, 0.f};
    for (int base = s; base < e; base += 64) {
        int nE = min(64, e - base);
        int msrc = (lane < nE) ? (int)csr_src[base + lane] : 0;
#pragma unroll
        for (int rr = 0; rr < 8; ++rr) {
            int i = rr * 8;
            if (i >= nE) break;
            int myi = i + grp;
            int src = __shfl(msrc, myi, 64);
            bool ok = myi < nE;
            int srcx = ok ? src : node;
            short8v v = *(const short8v*)&hw2[(size_t)srcx * 64 + gl * 8];
            if (ok) {
#pragma unroll
                for (int j = 0; j < 8; ++j) acc[j] += bf2f((unsigned short)v[j]);
            }
        }
    }
#pragma unroll
    for (int off = 8; off <= 32; off <<= 1) {
#pragma unroll
        for (int j = 0; j < 8; ++j) acc[j] += __shfl_xor(acc[j], off, 64);
    }
    short8v sv = *(const short8v*)&hw2[(size_t)node * 64 + gl * 8];
#pragma unroll
    for (int j = 0; j < 8; ++j) acc[j] += bf2f((unsigned short)sv[j]);

    float di = dinv[node];
    float4 b0 = *(const float4*)&b[gl * 8];
    float4 b1 = *(const float4*)&b[gl * 8 + 4];
    float val[8];
    val[0] = di * acc[0] + b0.x;
    val[1] = di * acc[1] + b0.y;
    val[2] = di * acc[2] + b0.z;
    val[3] = di * acc[3] + b0.w;
    val[4] = di * acc[4] + b1.x;
    val[5] = di * acc[5] + b1.y;
    val[6] = di * acc[6] + b1.z;
    val[7] = di * acc[7] + b1.w;

    float sq = 0.f;
#pragma unroll
    for (int j = 0; j < 8; ++j) sq += val[j] * val[j];
#pragma unroll
    for (int off = 1; off <= 4; off <<= 1) sq += __shfl_xor(sq, off, 64);
    float inv = 1.0f / fmaxf(sqrtf(sq), 1e-12f);

    if (grp == 0) {
        float4 r0, r1;
        r0.x = fmaxf(val[0] * inv, 0.f);
        r0.y = fmaxf(val[1] * inv, 0.f);
        r0.z = fmaxf(val[2] * inv, 0.f);
        r0.w = fmaxf(val[3] * inv, 0.f);
        r1.x = fmaxf(val[4] * inv, 0.f);
        r1.y = fmaxf(val[5] * inv, 0.f);
        r1.z = fmaxf(val[6] * inv, 0.f);
        r1.w = fmaxf(val[7] * inv, 0.f);
        *(float4*)&sh[tid >> 6][gl * 8] = r0;
        *(float4*)&sh[tid >> 6][gl * 8 + 4] = r1;
    }
    __syncthreads();
    if (tid < 64) {
        int nb = blockIdx.x * 4;
        int gcur = batch[nb];
        float runsum = 0.f, runmax = 0.f;
#pragma unroll
        for (int w = 0; w < 4; ++w) {
            int g = batch[nb + w];
            if (g != gcur) {
                atomicAdd(&gsum[gcur * 64 + tid], runsum);
                atomicMax((int*)&gmax[gcur * 64 + tid], __float_as_int(runmax));
                runsum = 0.f; runmax = 0.f; gcur = g;
            }
            float v = sh[w][tid];
            runsum += v;
            runmax = fmaxf(runmax, v);
        }
        atomicAdd(&gsum[gcur * 64 + tid], runsum);
        atomicMax((int*)&gmax[gcur * 64 + tid], __float_as_int(runmax));
    }
}

// Phase-2: one block per graph; mean + concat + 128x32 linear.
__global__ __launch_bounds__(128) void linear_kernel(const float* __restrict__ gsum,
                                                     const float* __restrict__ gmax,
                                                     const int* __restrict__ gstart,
                                                     const float* __restrict__ Wl,
                                                     const float* __restrict__ bl,
                                                     float* __restrict__ out) {
    int g = blockIdx.x;
    __shared__ float pooled[128];
    int t = threadIdx.x;
    if (t < 64) {
        int cnt = gstart[g + 1] - gstart[g];
        pooled[t] = gsum[g * 64 + t] / fmaxf((float)cnt, 1.0f);
    } else {
        pooled[t] = gmax[g * 64 + (t - 64)];
    }
    __syncthreads();
    if (t < 32) {
        float acc = bl[t];
#pragma unroll 8
        for (int k = 0; k < 128; ++k) acc += pooled[k] * Wl[k * 32 + t];
        out[g * 32 + t] = acc;
    }
}

extern "C" void kernel_launch(void* const* d_in, const int* in_sizes, int n_in,
                              void* d_out, int out_size, void* d_ws, size_t ws_size,
                              hipStream_t stream) {
    const float* x        = (const float*)d_in[0];   // 50000 x 128
    const int*   ei       = (const int*)d_in[1];     // 2 x 800000
    const int*   batch    = (const int*)d_in[2];     // 50000
    const float* W1       = (const float*)d_in[3];   // 128 x 64
    const float* b1       = (const float*)d_in[4];
    const float* W2       = (const float*)d_in[5];   // 64 x 64
    const float* b2       = (const float*)d_in[6];
    const float* W3       = (const float*)d_in[7];   // 64 x 64
    const float* b3       = (const float*)d_in[8];
    const float* Wl       = (const float*)d_in[9];   // 128 x 32
    const float* bl       = (const float*)d_in[10];
    float* out = (float*)d_out;

    char* ws = (char*)d_ws;
    int*   cnt      = (int*)ws;                 ws += align256((size_t)N_NODES * 4);
    int*   incl     = (int*)ws;                 ws += align256((size_t)N_NODES * 4);
    int*   bsum     = (int*)ws;                 ws += align256((size_t)SCAN_NB * 4);
    int*   boff     = (int*)ws;                 ws += align256((size_t)SCAN_NB * 4);
    int*   row_ptr  = (int*)ws;                 ws += align256((size_t)(N_NODES + 1) * 4);
    int*   fill_ptr = (int*)ws;                 ws += align256((size_t)N_NODES * 4);
    float* dinv     = (float*)ws;               ws += align256((size_t)N_NODES * 4);
    int*   gstart   = (int*)ws;                 ws += align256((size_t)(N_GRAPHS + 1) * 4);
    float* gsum     = (float*)ws;               ws += (size_t)N_GRAPHS * 64 * 4;   // contiguous
    float* gmax     = (float*)ws;               ws += align256((size_t)N_GRAPHS * 64 * 4);
    unsigned short* csr_src = (unsigned short*)ws; ws += align256((size_t)N_EDGES * 2);
    unsigned short* hwa = (unsigned short*)ws;  ws += align256((size_t)N_NODES * 64 * 2);
    unsigned short* hwb = (unsigned short*)ws;  ws += align256((size_t)N_NODES * 64 * 2);

    hipLaunchKernelGGL(zero2, dim3((N_NODES + 2 * N_GRAPHS * 64 + 255) / 256), dim3(256), 0,
                       stream, cnt, N_NODES, (int*)gsum, 2 * N_GRAPHS * 64);
    hipLaunchKernelGGL(deg_kernel, dim3((N_EDGES + 255) / 256), dim3(256), 0, stream, ei, cnt);
    hipLaunchKernelGGL(scan_a, dim3(SCAN_NB), dim3(256), 0, stream, cnt, incl, bsum);
    hipLaunchKernelGGL(scan_b_gstart, dim3(1), dim3(384), 0, stream, bsum, boff, batch, gstart);
    hipLaunchKernelGGL(scan_c, dim3(SCAN_NB), dim3(256), 0, stream,
                       cnt, incl, boff, row_ptr, fill_ptr, dinv);

    // fill (CSR scatter, u16, 4 edges/thread) and layer-1 matmul overlap
    hipLaunchKernelGGL(fill_mm1_kernel, dim3(MM1_BLOCKS + FILL_BLOCKS), dim3(256), 0, stream,
                       ei, fill_ptr, csr_src, x, W1, dinv, hwa);

    const int aggmm_grid = N_NODES / 16;   // 3125, exact
    const int aggp_grid  = N_NODES / 4;    // 12500, exact

    // layer-1 agg + fused W2 matmul -> hwb
    hipLaunchKernelGGL(aggmm_kernel, dim3(aggmm_grid), dim3(1024), 0, stream,
                       hwa, row_ptr, csr_src, dinv, b1, W2, hwb);
    // layer-2 agg + fused W3 matmul -> hwa
    hipLaunchKernelGGL(aggmm_kernel, dim3(aggmm_grid), dim3(1024), 0, stream,
                       hwb, row_ptr, csr_src, dinv, b2, W3, hwa);
    // layer-3 agg + fused pooling
    hipLaunchKernelGGL(agg_pool_kernel, dim3(aggp_grid), dim3(256), 0, stream,
                       hwa, row_ptr, csr_src, dinv, b3, batch, gsum, gmax);

    // final linear
    hipLaunchKernelGGL(linear_kernel, dim3(N_GRAPHS), dim3(128), 0, stream,
                       gsum, gmax, gstart, Wl, bl, out);
}